// Round 11
// baseline (377.393 us; speedup 1.0000x reference)
//
#include <hip/hip_runtime.h>
#include <hip/hip_bf16.h>
#include <math.h>

// OLMoE sparse MoE block: E=32, K=4, H=2048, F=1024, T=1024 tokens.
#define NE 32
#define NK 4
#define NH 2048
#define NF 1024
#define NT 1024

#define BM 192      // pairs per tile: 1 tile/expert for n_e <= 192 (typ. ~128)
#define BN 128      // output cols per block: 512 B contiguous per weight row
#define BK 64
#define MAXTILES 64

typedef __attribute__((ext_vector_type(8))) short short8;
typedef __attribute__((ext_vector_type(4))) float f32x4;

#define ASMV(s) asm volatile(s ::: "memory")
#define SCHED0() __builtin_amdgcn_sched_barrier(0)

// Workspace layout (bytes); total ~46 MB
static constexpr size_t OFF_CNT = 0;
static constexpr size_t OFF_ENT = 1024;
static constexpr size_t OFF_WTK = 1024 + 32 * 1024 * 4;
static constexpr size_t OFF_TIL = 200704;
static constexpr size_t OFF_XB  = 262144;
static constexpr size_t OFF_ACT = OFF_XB + (size_t)NT * NH * 2;
static constexpr size_t OFF_YP  = OFF_ACT + (size_t)NT * NK * NF * 2;

// ---------------------------------------------------------------------------
__device__ inline unsigned bfbits(float f) {
  return (unsigned)__builtin_bit_cast(unsigned short, __float2bfloat16(f));
}
__device__ inline unsigned pkbf(float lo, float hi) {
  return bfbits(lo) | (bfbits(hi) << 16);
}
// XOR-swizzled element index for a [rows][64] bf16 tile (row stride 128 B).
__device__ inline int swz(int r, int k) {
  int key = ((r & 7) ^ ((r >> 2) & 7)) & 7;
  int b = (r << 7) | (k << 1);
  return (b ^ (key << 4)) >> 1;
}

// ---------------------------------------------------------------------------
// Kernel 1: router (unchanged, validated).
// ---------------------------------------------------------------------------
__global__ __launch_bounds__(256) void router_kernel(
    const float* __restrict__ x, const float* __restrict__ gate_w,
    float* __restrict__ logits_out, int* __restrict__ cnt,
    int* __restrict__ entries, float* __restrict__ w_tk,
    unsigned short* __restrict__ xb) {
  __shared__ float xs[NH];
  __shared__ float logits_s[NE];
  const int t = blockIdx.x;
  const int tid = threadIdx.x;

  for (int i = tid; i < NH / 4; i += 256) {
    *reinterpret_cast<float4*>(&xs[i * 4]) =
        *reinterpret_cast<const float4*>(&x[(size_t)t * NH + i * 4]);
  }
  __syncthreads();

  {
    unsigned u[4];
#pragma unroll
    for (int j = 0; j < 4; ++j)
      u[j] = pkbf(xs[tid * 8 + 2 * j], xs[tid * 8 + 2 * j + 1]);
    *reinterpret_cast<uint4*>(&xb[(size_t)t * NH + tid * 8]) =
        make_uint4(u[0], u[1], u[2], u[3]);
  }

  const int wave = tid >> 6, lane = tid & 63;
  for (int ei = 0; ei < 8; ++ei) {
    const int e = wave * 8 + ei;
    const float* gw = gate_w + (size_t)e * NH;
    float s = 0.f;
    for (int h = lane; h < NH; h += 64) s += xs[h] * gw[h];
#pragma unroll
    for (int off = 32; off >= 1; off >>= 1) s += __shfl_xor(s, off, 64);
    if (lane == 0) logits_s[e] = s;
  }
  __syncthreads();

  if (wave == 0) {
    float v = (lane < NE) ? logits_s[lane] : -INFINITY;
    if (lane < NE) logits_out[(size_t)t * NE + lane] = v;
    float m = v;
#pragma unroll
    for (int off = 32; off >= 1; off >>= 1) m = fmaxf(m, __shfl_xor(m, off, 64));
    float ex = (lane < NE) ? expf(v - m) : 0.f;
    float sum = ex;
#pragma unroll
    for (int off = 32; off >= 1; off >>= 1) sum += __shfl_xor(sum, off, 64);
    float pv = (lane < NE) ? (ex / sum) : -1.f;
    for (int k = 0; k < NK; ++k) {
      float bv = pv;
      int bi = lane;
#pragma unroll
      for (int off = 32; off >= 1; off >>= 1) {
        float ov = __shfl_xor(bv, off, 64);
        int oi = __shfl_xor(bi, off, 64);
        if (ov > bv || (ov == bv && oi < bi)) { bv = ov; bi = oi; }
      }
      if (lane == 0) {
        int pos = atomicAdd(&cnt[bi], 1);
        entries[bi * NT + pos] = t * NK + k;
        w_tk[t * NK + k] = bv;
      }
      if (lane == bi) pv = -1.f;
    }
  }
}

// ---------------------------------------------------------------------------
// Kernel 1b: compact (expert, rowtile) tile table.
// ---------------------------------------------------------------------------
__global__ __launch_bounds__(64) void build_tiles(
    const int* __restrict__ cnt, int* __restrict__ tile_hdr) {
  const int lane = threadIdx.x;
  int c = (lane < NE) ? cnt[lane] : 0;
  int nt = (c + BM - 1) / BM;
  int pre = nt;
#pragma unroll
  for (int d = 1; d < 32; d <<= 1) {
    int v = __shfl_up(pre, d, 64);
    if (lane >= d) pre += v;
  }
  int start = pre - nt;
  if (lane < NE) {
    for (int i = 0; i < nt; ++i) tile_hdr[1 + start + i] = (lane << 4) | i;
  }
  if (lane == NE - 1) tile_hdr[0] = pre;
}

// ---------------------------------------------------------------------------
// Kernel 2: gate+up MFMA GEMM + SwiGLU. Tile 192(pairs) x 128(f), K=2048.
// 512 threads = 8 waves (4m x 2n); wave tile 48m x 64n (3mf x 4nf).
// B: dwordx4 loads -> TWO named reg slots (distance 2) -> bf16 -> swizzled
//    LDS dbuf. A: bf16 regs, double-buffered (distance 1). Issue order
//    pinned with sched_barrier(0); storeB's auto vmcnt leaves next loads
//    in flight. One lgkmcnt(0)+s_barrier per K-step.
// grid = (NF/128=8, MAXTILES).
// ---------------------------------------------------------------------------
__global__ __launch_bounds__(512) void phase1_mfma(
    const unsigned short* __restrict__ xb, const float* __restrict__ wg,
    const float* __restrict__ wu, const int* __restrict__ tile_hdr,
    const int* __restrict__ entries, const int* __restrict__ cnt,
    unsigned short* __restrict__ act) {
  const int s = blockIdx.y;
  if (s >= tile_hdr[0]) return;
  const int packed = tile_hdr[1 + s];
  const int e = packed >> 4, rt = packed & 15;
  const int n_e = cnt[e];
  const int f0 = blockIdx.x * BN;

  __shared__ unsigned short Bgs[2][BN * BK];  // 2 x 16 KB, [n][k] swizzled
  __shared__ unsigned short Bus[2][BN * BK];  // 2 x 16 KB
  __shared__ int pair_s[BM];

  const int tid = threadIdx.x;
  if (tid < BM) {
    int idx = rt * BM + tid;
    pair_s[tid] = (idx < n_e) ? entries[e * NT + idx] : -1;
  }
  __syncthreads();

  const int lane = tid & 63, wid = tid >> 6;
  const int wm = (wid >> 1) * 48, wn = (wid & 1) * 64;
  const int lm = lane & 15, lk = (lane >> 4) * 8;

  // A row pointers (3 m-frags per wave)
  const unsigned short* aptr[3];
#pragma unroll
  for (int mf = 0; mf < 3; ++mf) {
    int p = pair_s[wm + mf * 16 + lm];
    int tok = (p >= 0) ? (p >> 2) : 0;
    aptr[mf] = xb + (size_t)tok * NH + lk;
  }

  // B staging roles: f-quad q = tid&31 (n = 4q..4q+3), k-quad g = tid>>5.
  const int q = tid & 31, g4 = (tid >> 5) * 4;
  const float* bgp = wg + (size_t)e * NH * NF + f0 + q * 4;
  const float* bup = wu + (size_t)e * NH * NF + f0 + q * 4;

  float rg0[4][4], ru0[4][4], rg1[4][4], ru1[4][4];  // two named B slots
  short8 a0[3][2], a1[3][2];                          // A cur/next

  f32x4 accg[3][4], accu[3][4];
#pragma unroll
  for (int i = 0; i < 3; ++i)
#pragma unroll
    for (int j = 0; j < 4; ++j) {
      accg[i][j] = (f32x4)(0.f);
      accu[i][j] = (f32x4)(0.f);
    }

  auto loadA = [&](int k0, short8 (&a)[3][2]) {
#pragma unroll
    for (int mf = 0; mf < 3; ++mf)
#pragma unroll
      for (int kc = 0; kc < 2; ++kc)
        a[mf][kc] = *reinterpret_cast<const short8*>(aptr[mf] + k0 + kc * 32);
  };
  auto loadB = [&](int k0, float (&rg)[4][4], float (&ru)[4][4]) {
#pragma unroll
    for (int i = 0; i < 4; ++i) {
      const size_t off = (size_t)(k0 + g4 + i) * NF;
      float4 vg = *reinterpret_cast<const float4*>(bgp + off);
      float4 vu = *reinterpret_cast<const float4*>(bup + off);
      rg[i][0] = vg.x; rg[i][1] = vg.y; rg[i][2] = vg.z; rg[i][3] = vg.w;
      ru[i][0] = vu.x; ru[i][1] = vu.y; ru[i][2] = vu.z; ru[i][3] = vu.w;
    }
  };
  auto storeB = [&](const float (&rg)[4][4], const float (&ru)[4][4], int b) {
#pragma unroll
    for (int j = 0; j < 4; ++j) {
      const int n = q * 4 + j;
      uint2 cg, cu;
      cg.x = pkbf(rg[0][j], rg[1][j]); cg.y = pkbf(rg[2][j], rg[3][j]);
      cu.x = pkbf(ru[0][j], ru[1][j]); cu.y = pkbf(ru[2][j], ru[3][j]);
      *reinterpret_cast<uint2*>(&Bgs[b][swz(n, g4)]) = cg;
      *reinterpret_cast<uint2*>(&Bus[b][swz(n, g4)]) = cu;
    }
  };
  auto compute = [&](int c, const short8 (&a)[3][2]) {
#pragma unroll
    for (int kc = 0; kc < 2; ++kc) {
      short8 bg[4], bu[4];
#pragma unroll
      for (int nf = 0; nf < 4; ++nf) {
        bg[nf] = *reinterpret_cast<const short8*>(
            &Bgs[c][swz(wn + nf * 16 + lm, kc * 32 + lk)]);
        bu[nf] = *reinterpret_cast<const short8*>(
            &Bus[c][swz(wn + nf * 16 + lm, kc * 32 + lk)]);
      }
#pragma unroll
      for (int mf = 0; mf < 3; ++mf)
#pragma unroll
        for (int nf = 0; nf < 4; ++nf) {
          accg[mf][nf] = __builtin_amdgcn_mfma_f32_16x16x32_bf16(a[mf][kc], bg[nf], accg[mf][nf], 0, 0, 0);
          accu[mf][nf] = __builtin_amdgcn_mfma_f32_16x16x32_bf16(a[mf][kc], bu[nf], accu[mf][nf], 0, 0, 0);
        }
    }
  };

  const int NS = NH / BK;  // 32 (even)
  // prologue: B(0)->buf0 staged; B(1) in slot1 (in flight); A(0) in a0
  loadB(0, rg0, ru0);
  loadB(BK, rg1, ru1);
  loadA(0, a0);
  storeB(rg0, ru0, 0);       // auto-waits slot0 only
  ASMV("s_waitcnt lgkmcnt(0)");
  __builtin_amdgcn_s_barrier();
  SCHED0();

  for (int t = 0; t < NS - 2; t += 2) {
    // even: compute buf0 with a0; slot1 holds B(t+1)
    loadB((t + 2) * BK, rg0, ru0);   // slot0 free (B(t) in LDS)
    loadA((t + 1) * BK, a1);
    SCHED0();                        // pin: issues precede compute
    compute(0, a0);
    SCHED0();                        // pin: compute precedes storeB wait
    storeB(rg1, ru1, 1);             // auto vmcnt leaves B(t+2)+A(t+1) in flight
    ASMV("s_waitcnt lgkmcnt(0)");
    __builtin_amdgcn_s_barrier();
    SCHED0();
    // odd: compute buf1 with a1; slot0 holds B(t+2)
    loadB((t + 3) * BK, rg1, ru1);
    loadA((t + 2) * BK, a0);
    SCHED0();
    compute(1, a1);
    SCHED0();
    storeB(rg0, ru0, 0);
    ASMV("s_waitcnt lgkmcnt(0)");
    __builtin_amdgcn_s_barrier();
    SCHED0();
  }
  // tail: t = NS-2 (buf0, a0), NS-1 (buf1, a1); B(NS-1) in slot1
  loadA((NS - 1) * BK, a1);
  SCHED0();
  compute(0, a0);
  SCHED0();
  storeB(rg1, ru1, 1);
  ASMV("s_waitcnt lgkmcnt(0)");
  __builtin_amdgcn_s_barrier();
  SCHED0();
  compute(1, a1);

  // epilogue: silu(g)*u -> act bf16. D layout: col=lane&15, row=(lane>>4)*4+r.
  const int rbase = wm + (lane >> 4) * 4;
#pragma unroll
  for (int mf = 0; mf < 3; ++mf) {
#pragma unroll
    for (int r = 0; r < 4; ++r) {
      const int row = rbase + mf * 16 + r;
      const int p = pair_s[row];
      if (p < 0) continue;
#pragma unroll
      for (int nf = 0; nf < 4; ++nf) {
        float gg = accg[mf][nf][r], uu = accu[mf][nf][r];
        float o = (gg / (1.f + __expf(-gg))) * uu;
        act[(size_t)p * NF + f0 + wn + nf * 16 + lm] = (unsigned short)bfbits(o);
      }
    }
  }
}

// ---------------------------------------------------------------------------
// Kernel 3: down-proj MFMA GEMM, same distance-2 structure. Tile 192 x 128
// over H, K=F=1024, 512 threads. grid = (NH/128=16, MAXTILES).
// ---------------------------------------------------------------------------
__global__ __launch_bounds__(512) void phase2_mfma(
    const unsigned short* __restrict__ act, const float* __restrict__ wd,
    const int* __restrict__ tile_hdr, const int* __restrict__ entries,
    const int* __restrict__ cnt, float* __restrict__ yp) {
  const int s = blockIdx.y;
  if (s >= tile_hdr[0]) return;
  const int packed = tile_hdr[1 + s];
  const int e = packed >> 4, rt = packed & 15;
  const int n_e = cnt[e];
  const int h0 = blockIdx.x * BN;

  __shared__ unsigned short Bs[2][BN * BK];  // 2 x 16 KB
  __shared__ int pair_s[BM];

  const int tid = threadIdx.x;
  if (tid < BM) {
    int idx = rt * BM + tid;
    pair_s[tid] = (idx < n_e) ? entries[e * NT + idx] : -1;
  }
  __syncthreads();

  const int lane = tid & 63, wid = tid >> 6;
  const int wm = (wid >> 1) * 48, wn = (wid & 1) * 64;
  const int lm = lane & 15, lk = (lane >> 4) * 8;

  const unsigned short* aptr[3];
#pragma unroll
  for (int mf = 0; mf < 3; ++mf) {
    int p = pair_s[wm + mf * 16 + lm];
    int pa = (p >= 0) ? p : 0;
    aptr[mf] = act + (size_t)pa * NF + lk;
  }

  const int q = tid & 31, g4 = (tid >> 5) * 4;
  const float* bdp = wd + (size_t)e * NF * NH + h0 + q * 4;

  float rd0[4][4], rd1[4][4];
  short8 a0[3][2], a1[3][2];

  f32x4 acc[3][4];
#pragma unroll
  for (int i = 0; i < 3; ++i)
#pragma unroll
    for (int j = 0; j < 4; ++j) acc[i][j] = (f32x4)(0.f);

  auto loadA = [&](int k0, short8 (&a)[3][2]) {
#pragma unroll
    for (int mf = 0; mf < 3; ++mf)
#pragma unroll
      for (int kc = 0; kc < 2; ++kc)
        a[mf][kc] = *reinterpret_cast<const short8*>(aptr[mf] + k0 + kc * 32);
  };
  auto loadB = [&](int k0, float (&rd)[4][4]) {
#pragma unroll
    for (int i = 0; i < 4; ++i) {
      float4 v = *reinterpret_cast<const float4*>(bdp + (size_t)(k0 + g4 + i) * NH);
      rd[i][0] = v.x; rd[i][1] = v.y; rd[i][2] = v.z; rd[i][3] = v.w;
    }
  };
  auto storeB = [&](const float (&rd)[4][4], int b) {
#pragma unroll
    for (int j = 0; j < 4; ++j) {
      const int n = q * 4 + j;
      uint2 cd;
      cd.x = pkbf(rd[0][j], rd[1][j]); cd.y = pkbf(rd[2][j], rd[3][j]);
      *reinterpret_cast<uint2*>(&Bs[b][swz(n, g4)]) = cd;
    }
  };
  auto compute = [&](int c, const short8 (&a)[3][2]) {
#pragma unroll
    for (int kc = 0; kc < 2; ++kc) {
      short8 b2[4];
#pragma unroll
      for (int nf = 0; nf < 4; ++nf)
        b2[nf] = *reinterpret_cast<const short8*>(
            &Bs[c][swz(wn + nf * 16 + lm, kc * 32 + lk)]);
#pragma unroll
      for (int mf = 0; mf < 3; ++mf)
#pragma unroll
        for (int nf = 0; nf < 4; ++nf)
          acc[mf][nf] = __builtin_amdgcn_mfma_f32_16x16x32_bf16(a[mf][kc], b2[nf], acc[mf][nf], 0, 0, 0);
    }
  };

  const int NS = NF / BK;  // 16 (even)
  loadB(0, rd0);
  loadB(BK, rd1);
  loadA(0, a0);
  storeB(rd0, 0);
  ASMV("s_waitcnt lgkmcnt(0)");
  __builtin_amdgcn_s_barrier();
  SCHED0();

  for (int t = 0; t < NS - 2; t += 2) {
    loadB((t + 2) * BK, rd0);
    loadA((t + 1) * BK, a1);
    SCHED0();
    compute(0, a0);
    SCHED0();
    storeB(rd1, 1);
    ASMV("s_waitcnt lgkmcnt(0)");
    __builtin_amdgcn_s_barrier();
    SCHED0();
    loadB((t + 3) * BK, rd1);
    loadA((t + 2) * BK, a0);
    SCHED0();
    compute(1, a1);
    SCHED0();
    storeB(rd0, 0);
    ASMV("s_waitcnt lgkmcnt(0)");
    __builtin_amdgcn_s_barrier();
    SCHED0();
  }
  loadA((NS - 1) * BK, a1);
  SCHED0();
  compute(0, a0);
  SCHED0();
  storeB(rd1, 1);
  ASMV("s_waitcnt lgkmcnt(0)");
  __builtin_amdgcn_s_barrier();
  SCHED0();
  compute(1, a1);

  const int rbase = wm + (lane >> 4) * 4;
#pragma unroll
  for (int mf = 0; mf < 3; ++mf) {
#pragma unroll
    for (int r = 0; r < 4; ++r) {
      const int row = rbase + mf * 16 + r;
      const int p = pair_s[row];
      if (p < 0) continue;
#pragma unroll
      for (int nf = 0; nf < 4; ++nf)
        yp[(size_t)p * NH + h0 + wn + nf * 16 + lm] = acc[mf][nf][r];
    }
  }
}

// ---------------------------------------------------------------------------
// Kernel 4: combine (unchanged).
// ---------------------------------------------------------------------------
__global__ __launch_bounds__(256) void combine_kernel(
    const float* __restrict__ yp, const float* __restrict__ w_tk,
    float* __restrict__ out) {
  const size_t idx = (size_t)blockIdx.x * 256 + threadIdx.x;
  const int t = (int)(idx >> 9);
  const int h4 = (int)(idx & 511) * 4;
  float4 s = make_float4(0.f, 0.f, 0.f, 0.f);
#pragma unroll
  for (int k = 0; k < NK; ++k) {
    const float w = w_tk[t * NK + k];
    const float4 v = *reinterpret_cast<const float4*>(
        &yp[((size_t)(t * NK + k)) * NH + h4]);
    s.x += w * v.x; s.y += w * v.y; s.z += w * v.z; s.w += w * v.w;
  }
  *reinterpret_cast<float4*>(&out[(size_t)t * NH + h4]) = s;
}

// ---------------------------------------------------------------------------
extern "C" void kernel_launch(void* const* d_in, const int* in_sizes, int n_in,
                              void* d_out, int out_size, void* d_ws,
                              size_t ws_size, hipStream_t stream) {
  const float* x      = (const float*)d_in[0];
  const float* gate_w = (const float*)d_in[1];
  const float* wg     = (const float*)d_in[2];
  const float* wu     = (const float*)d_in[3];
  const float* wd     = (const float*)d_in[4];

  float* out        = (float*)d_out;
  float* logits_out = (float*)d_out + (size_t)NT * NH;

  char* ws = (char*)d_ws;
  int* cnt            = (int*)(ws + OFF_CNT);
  int* entries        = (int*)(ws + OFF_ENT);
  float* w_tk         = (float*)(ws + OFF_WTK);
  int* tile_hdr       = (int*)(ws + OFF_TIL);
  unsigned short* xb  = (unsigned short*)(ws + OFF_XB);
  unsigned short* act = (unsigned short*)(ws + OFF_ACT);
  float* yp           = (float*)(ws + OFF_YP);

  hipMemsetAsync(ws, 0, 1024, stream);  // zero expert counters

  router_kernel<<<NT, 256, 0, stream>>>(x, gate_w, logits_out, cnt, entries, w_tk, xb);
  build_tiles<<<1, 64, 0, stream>>>(cnt, tile_hdr);
  phase1_mfma<<<dim3(NF / BN, MAXTILES), 512, 0, stream>>>(xb, wg, wu, tile_hdr, entries, cnt, act);
  phase2_mfma<<<dim3(NH / BN, MAXTILES), 512, 0, stream>>>(act, wd, tile_hdr, entries, cnt, yp);
  combine_kernel<<<(NT * NH / 4) / 256, 256, 0, stream>>>(yp, w_tk, out);
}

// Round 12
// 330.086 us; speedup vs baseline: 1.1433x; 1.1433x over previous
//
#include <hip/hip_runtime.h>
#include <hip/hip_bf16.h>
#include <math.h>

// OLMoE sparse MoE block: E=32, K=4, H=2048, F=1024, T=1024 tokens.
#define NE 32
#define NK 4
#define NH 2048
#define NF 1024
#define NT 1024

#define BM 192      // pairs per tile: 1 tile/expert for n_e <= 192 (typ. ~128)
#define BN 128      // output cols per block: 512 B contiguous per weight row
#define BK 64
#define MAXTILES 64

typedef __attribute__((ext_vector_type(8))) short short8;
typedef __attribute__((ext_vector_type(4))) float f32x4;

#define ASMV(s) asm volatile(s ::: "memory")
#define SCHED0() __builtin_amdgcn_sched_barrier(0)

// Workspace layout (bytes); total ~46 MB
static constexpr size_t OFF_CNT = 0;
static constexpr size_t OFF_ENT = 1024;
static constexpr size_t OFF_WTK = 1024 + 32 * 1024 * 4;
static constexpr size_t OFF_TIL = 200704;
static constexpr size_t OFF_XB  = 262144;
static constexpr size_t OFF_ACT = OFF_XB + (size_t)NT * NH * 2;
static constexpr size_t OFF_YP  = OFF_ACT + (size_t)NT * NK * NF * 2;

// ---------------------------------------------------------------------------
__device__ inline unsigned bfbits(float f) {
  return (unsigned)__builtin_bit_cast(unsigned short, __float2bfloat16(f));
}
__device__ inline unsigned pkbf(float lo, float hi) {
  return bfbits(lo) | (bfbits(hi) << 16);
}
// XOR-swizzled element index for a [rows][64] bf16 tile (row stride 128 B).
__device__ inline int swz(int r, int k) {
  int key = ((r & 7) ^ ((r >> 2) & 7)) & 7;
  int b = (r << 7) | (k << 1);
  return (b ^ (key << 4)) >> 1;
}

// ---------------------------------------------------------------------------
// Kernel 1: router (unchanged, validated).
// ---------------------------------------------------------------------------
__global__ __launch_bounds__(256) void router_kernel(
    const float* __restrict__ x, const float* __restrict__ gate_w,
    float* __restrict__ logits_out, int* __restrict__ cnt,
    int* __restrict__ entries, float* __restrict__ w_tk,
    unsigned short* __restrict__ xb) {
  __shared__ float xs[NH];
  __shared__ float logits_s[NE];
  const int t = blockIdx.x;
  const int tid = threadIdx.x;

  for (int i = tid; i < NH / 4; i += 256) {
    *reinterpret_cast<float4*>(&xs[i * 4]) =
        *reinterpret_cast<const float4*>(&x[(size_t)t * NH + i * 4]);
  }
  __syncthreads();

  {
    unsigned u[4];
#pragma unroll
    for (int j = 0; j < 4; ++j)
      u[j] = pkbf(xs[tid * 8 + 2 * j], xs[tid * 8 + 2 * j + 1]);
    *reinterpret_cast<uint4*>(&xb[(size_t)t * NH + tid * 8]) =
        make_uint4(u[0], u[1], u[2], u[3]);
  }

  const int wave = tid >> 6, lane = tid & 63;
  for (int ei = 0; ei < 8; ++ei) {
    const int e = wave * 8 + ei;
    const float* gw = gate_w + (size_t)e * NH;
    float s = 0.f;
    for (int h = lane; h < NH; h += 64) s += xs[h] * gw[h];
#pragma unroll
    for (int off = 32; off >= 1; off >>= 1) s += __shfl_xor(s, off, 64);
    if (lane == 0) logits_s[e] = s;
  }
  __syncthreads();

  if (wave == 0) {
    float v = (lane < NE) ? logits_s[lane] : -INFINITY;
    if (lane < NE) logits_out[(size_t)t * NE + lane] = v;
    float m = v;
#pragma unroll
    for (int off = 32; off >= 1; off >>= 1) m = fmaxf(m, __shfl_xor(m, off, 64));
    float ex = (lane < NE) ? expf(v - m) : 0.f;
    float sum = ex;
#pragma unroll
    for (int off = 32; off >= 1; off >>= 1) sum += __shfl_xor(sum, off, 64);
    float pv = (lane < NE) ? (ex / sum) : -1.f;
    for (int k = 0; k < NK; ++k) {
      float bv = pv;
      int bi = lane;
#pragma unroll
      for (int off = 32; off >= 1; off >>= 1) {
        float ov = __shfl_xor(bv, off, 64);
        int oi = __shfl_xor(bi, off, 64);
        if (ov > bv || (ov == bv && oi < bi)) { bv = ov; bi = oi; }
      }
      if (lane == 0) {
        int pos = atomicAdd(&cnt[bi], 1);
        entries[bi * NT + pos] = t * NK + k;
        w_tk[t * NK + k] = bv;
      }
      if (lane == bi) pv = -1.f;
    }
  }
}

// ---------------------------------------------------------------------------
// Kernel 1b: compact (expert, rowtile) tile table.
// ---------------------------------------------------------------------------
__global__ __launch_bounds__(64) void build_tiles(
    const int* __restrict__ cnt, int* __restrict__ tile_hdr) {
  const int lane = threadIdx.x;
  int c = (lane < NE) ? cnt[lane] : 0;
  int nt = (c + BM - 1) / BM;
  int pre = nt;
#pragma unroll
  for (int d = 1; d < 32; d <<= 1) {
    int v = __shfl_up(pre, d, 64);
    if (lane >= d) pre += v;
  }
  int start = pre - nt;
  if (lane < NE) {
    for (int i = 0; i < nt; ++i) tile_hdr[1 + start + i] = (lane << 4) | i;
  }
  if (lane == NE - 1) tile_hdr[0] = pre;
}

// ---------------------------------------------------------------------------
// Kernel 2: gate+up MFMA GEMM + SwiGLU. Tile 192(pairs) x 128(f), K=2048.
// 512 threads = 8 waves (4m x 2n); wave tile 48m x 64n (3mf x 4nf).
// R10 structure (distance-1, VGPR~108, no spill) + sched_barrier(0) pins so
// the B(t+1)/A(t) issues are EMITTED before compute (anti-sink), keeping one
// compute-phase of memory latency covered.
// grid = (NF/128=8, MAXTILES).
// ---------------------------------------------------------------------------
__global__ __launch_bounds__(512) void phase1_mfma(
    const unsigned short* __restrict__ xb, const float* __restrict__ wg,
    const float* __restrict__ wu, const int* __restrict__ tile_hdr,
    const int* __restrict__ entries, const int* __restrict__ cnt,
    unsigned short* __restrict__ act) {
  const int s = blockIdx.y;
  if (s >= tile_hdr[0]) return;
  const int packed = tile_hdr[1 + s];
  const int e = packed >> 4, rt = packed & 15;
  const int n_e = cnt[e];
  const int f0 = blockIdx.x * BN;

  __shared__ unsigned short Bgs[2][BN * BK];  // 2 x 16 KB, [n][k] swizzled
  __shared__ unsigned short Bus[2][BN * BK];  // 2 x 16 KB
  __shared__ int pair_s[BM];

  const int tid = threadIdx.x;
  if (tid < BM) {
    int idx = rt * BM + tid;
    pair_s[tid] = (idx < n_e) ? entries[e * NT + idx] : -1;
  }
  __syncthreads();

  const int lane = tid & 63, wid = tid >> 6;
  const int wm = (wid >> 1) * 48, wn = (wid & 1) * 64;
  const int lm = lane & 15, lk = (lane >> 4) * 8;

  // A row pointers (3 m-frags per wave)
  const unsigned short* aptr[3];
#pragma unroll
  for (int mf = 0; mf < 3; ++mf) {
    int p = pair_s[wm + mf * 16 + lm];
    int tok = (p >= 0) ? (p >> 2) : 0;
    aptr[mf] = xb + (size_t)tok * NH + lk;
  }

  // B staging roles: f-quad q = tid&31 (n = 4q..4q+3), k-quad g = tid>>5.
  const int q = tid & 31, g4 = (tid >> 5) * 4;
  const float* bgp = wg + (size_t)e * NH * NF + f0 + q * 4;
  const float* bup = wu + (size_t)e * NH * NF + f0 + q * 4;

  float rg[4][4], ru[4][4];  // [k-sub][f-sub]  (single slot, distance 1)
  short8 a[3][2];            // A frags, current iter

  f32x4 accg[3][4], accu[3][4];
#pragma unroll
  for (int i = 0; i < 3; ++i)
#pragma unroll
    for (int j = 0; j < 4; ++j) {
      accg[i][j] = (f32x4)(0.f);
      accu[i][j] = (f32x4)(0.f);
    }

  auto loadA = [&](int k0) {
#pragma unroll
    for (int mf = 0; mf < 3; ++mf)
#pragma unroll
      for (int kc = 0; kc < 2; ++kc)
        a[mf][kc] = *reinterpret_cast<const short8*>(aptr[mf] + k0 + kc * 32);
  };
  auto loadB = [&](int k0) {
#pragma unroll
    for (int i = 0; i < 4; ++i) {
      const size_t off = (size_t)(k0 + g4 + i) * NF;
      float4 vg = *reinterpret_cast<const float4*>(bgp + off);
      float4 vu = *reinterpret_cast<const float4*>(bup + off);
      rg[i][0] = vg.x; rg[i][1] = vg.y; rg[i][2] = vg.z; rg[i][3] = vg.w;
      ru[i][0] = vu.x; ru[i][1] = vu.y; ru[i][2] = vu.z; ru[i][3] = vu.w;
    }
  };
  auto storeB = [&](int b) {
#pragma unroll
    for (int j = 0; j < 4; ++j) {
      const int n = q * 4 + j;
      uint2 cg, cu;
      cg.x = pkbf(rg[0][j], rg[1][j]); cg.y = pkbf(rg[2][j], rg[3][j]);
      cu.x = pkbf(ru[0][j], ru[1][j]); cu.y = pkbf(ru[2][j], ru[3][j]);
      *reinterpret_cast<uint2*>(&Bgs[b][swz(n, g4)]) = cg;
      *reinterpret_cast<uint2*>(&Bus[b][swz(n, g4)]) = cu;
    }
  };
  auto compute = [&](int c) {
#pragma unroll
    for (int kc = 0; kc < 2; ++kc) {
      short8 bg[4], bu[4];
#pragma unroll
      for (int nf = 0; nf < 4; ++nf) {
        bg[nf] = *reinterpret_cast<const short8*>(
            &Bgs[c][swz(wn + nf * 16 + lm, kc * 32 + lk)]);
        bu[nf] = *reinterpret_cast<const short8*>(
            &Bus[c][swz(wn + nf * 16 + lm, kc * 32 + lk)]);
      }
#pragma unroll
      for (int mf = 0; mf < 3; ++mf)
#pragma unroll
        for (int nf = 0; nf < 4; ++nf) {
          accg[mf][nf] = __builtin_amdgcn_mfma_f32_16x16x32_bf16(a[mf][kc], bg[nf], accg[mf][nf], 0, 0, 0);
          accu[mf][nf] = __builtin_amdgcn_mfma_f32_16x16x32_bf16(a[mf][kc], bu[nf], accu[mf][nf], 0, 0, 0);
        }
    }
  };

  const int NS = NH / BK;  // 32
  // prologue: stage B(0) into buf0
  loadB(0);
  storeB(0);
  ASMV("s_waitcnt lgkmcnt(0)");
  __builtin_amdgcn_s_barrier();
  SCHED0();

  for (int t = 0; t < NS; ++t) {
    const int c = t & 1;
    loadA(t * BK);                        // A issue (L2-resident xb)
    if (t + 1 < NS) loadB((t + 1) * BK);  // B(t+1) issue
    SCHED0();  // PIN: loads above must be emitted before compute below
    compute(c);
    SCHED0();  // PIN: compute before storeB's vmcnt wait
    if (t + 1 < NS) {
      storeB(c ^ 1);                      // waits only the B regs (vmcnt auto)
      ASMV("s_waitcnt lgkmcnt(0)");
      __builtin_amdgcn_s_barrier();
      SCHED0();
    }
  }

  // epilogue: silu(g)*u -> act bf16. D layout: col=lane&15, row=(lane>>4)*4+r.
  const int rbase = wm + (lane >> 4) * 4;
#pragma unroll
  for (int mf = 0; mf < 3; ++mf) {
#pragma unroll
    for (int r = 0; r < 4; ++r) {
      const int row = rbase + mf * 16 + r;
      const int p = pair_s[row];
      if (p < 0) continue;
#pragma unroll
      for (int nf = 0; nf < 4; ++nf) {
        float gg = accg[mf][nf][r], uu = accu[mf][nf][r];
        float o = (gg / (1.f + __expf(-gg))) * uu;
        act[(size_t)p * NF + f0 + wn + nf * 16 + lm] = (unsigned short)bfbits(o);
      }
    }
  }
}

// ---------------------------------------------------------------------------
// Kernel 3: down-proj MFMA GEMM, same structure + pins. Tile 192 x 128 over
// H, K=F=1024, 512 threads. grid = (NH/128=16, MAXTILES).
// ---------------------------------------------------------------------------
__global__ __launch_bounds__(512) void phase2_mfma(
    const unsigned short* __restrict__ act, const float* __restrict__ wd,
    const int* __restrict__ tile_hdr, const int* __restrict__ entries,
    const int* __restrict__ cnt, float* __restrict__ yp) {
  const int s = blockIdx.y;
  if (s >= tile_hdr[0]) return;
  const int packed = tile_hdr[1 + s];
  const int e = packed >> 4, rt = packed & 15;
  const int n_e = cnt[e];
  const int h0 = blockIdx.x * BN;

  __shared__ unsigned short Bs[2][BN * BK];  // 2 x 16 KB
  __shared__ int pair_s[BM];

  const int tid = threadIdx.x;
  if (tid < BM) {
    int idx = rt * BM + tid;
    pair_s[tid] = (idx < n_e) ? entries[e * NT + idx] : -1;
  }
  __syncthreads();

  const int lane = tid & 63, wid = tid >> 6;
  const int wm = (wid >> 1) * 48, wn = (wid & 1) * 64;
  const int lm = lane & 15, lk = (lane >> 4) * 8;

  const unsigned short* aptr[3];
#pragma unroll
  for (int mf = 0; mf < 3; ++mf) {
    int p = pair_s[wm + mf * 16 + lm];
    int pa = (p >= 0) ? p : 0;
    aptr[mf] = act + (size_t)pa * NF + lk;
  }

  const int q = tid & 31, g4 = (tid >> 5) * 4;
  const float* bdp = wd + (size_t)e * NF * NH + h0 + q * 4;

  float rd[4][4];
  short8 a[3][2];

  f32x4 acc[3][4];
#pragma unroll
  for (int i = 0; i < 3; ++i)
#pragma unroll
    for (int j = 0; j < 4; ++j) acc[i][j] = (f32x4)(0.f);

  auto loadA = [&](int k0) {
#pragma unroll
    for (int mf = 0; mf < 3; ++mf)
#pragma unroll
      for (int kc = 0; kc < 2; ++kc)
        a[mf][kc] = *reinterpret_cast<const short8*>(aptr[mf] + k0 + kc * 32);
  };
  auto loadB = [&](int k0) {
#pragma unroll
    for (int i = 0; i < 4; ++i) {
      float4 v = *reinterpret_cast<const float4*>(bdp + (size_t)(k0 + g4 + i) * NH);
      rd[i][0] = v.x; rd[i][1] = v.y; rd[i][2] = v.z; rd[i][3] = v.w;
    }
  };
  auto storeB = [&](int b) {
#pragma unroll
    for (int j = 0; j < 4; ++j) {
      const int n = q * 4 + j;
      uint2 cd;
      cd.x = pkbf(rd[0][j], rd[1][j]); cd.y = pkbf(rd[2][j], rd[3][j]);
      *reinterpret_cast<uint2*>(&Bs[b][swz(n, g4)]) = cd;
    }
  };
  auto compute = [&](int c) {
#pragma unroll
    for (int kc = 0; kc < 2; ++kc) {
      short8 b2[4];
#pragma unroll
      for (int nf = 0; nf < 4; ++nf)
        b2[nf] = *reinterpret_cast<const short8*>(
            &Bs[c][swz(wn + nf * 16 + lm, kc * 32 + lk)]);
#pragma unroll
      for (int mf = 0; mf < 3; ++mf)
#pragma unroll
        for (int nf = 0; nf < 4; ++nf)
          acc[mf][nf] = __builtin_amdgcn_mfma_f32_16x16x32_bf16(a[mf][kc], b2[nf], acc[mf][nf], 0, 0, 0);
    }
  };

  const int NS = NF / BK;  // 16
  loadB(0);
  storeB(0);
  ASMV("s_waitcnt lgkmcnt(0)");
  __builtin_amdgcn_s_barrier();
  SCHED0();

  for (int t = 0; t < NS; ++t) {
    const int c = t & 1;
    loadA(t * BK);
    if (t + 1 < NS) loadB((t + 1) * BK);
    SCHED0();
    compute(c);
    SCHED0();
    if (t + 1 < NS) {
      storeB(c ^ 1);
      ASMV("s_waitcnt lgkmcnt(0)");
      __builtin_amdgcn_s_barrier();
      SCHED0();
    }
  }

  const int rbase = wm + (lane >> 4) * 4;
#pragma unroll
  for (int mf = 0; mf < 3; ++mf) {
#pragma unroll
    for (int r = 0; r < 4; ++r) {
      const int row = rbase + mf * 16 + r;
      const int p = pair_s[row];
      if (p < 0) continue;
#pragma unroll
      for (int nf = 0; nf < 4; ++nf)
        yp[(size_t)p * NH + h0 + wn + nf * 16 + lm] = acc[mf][nf][r];
    }
  }
}

// ---------------------------------------------------------------------------
// Kernel 4: combine (unchanged).
// ---------------------------------------------------------------------------
__global__ __launch_bounds__(256) void combine_kernel(
    const float* __restrict__ yp, const float* __restrict__ w_tk,
    float* __restrict__ out) {
  const size_t idx = (size_t)blockIdx.x * 256 + threadIdx.x;
  const int t = (int)(idx >> 9);
  const int h4 = (int)(idx & 511) * 4;
  float4 s = make_float4(0.f, 0.f, 0.f, 0.f);
#pragma unroll
  for (int k = 0; k < NK; ++k) {
    const float w = w_tk[t * NK + k];
    const float4 v = *reinterpret_cast<const float4*>(
        &yp[((size_t)(t * NK + k)) * NH + h4]);
    s.x += w * v.x; s.y += w * v.y; s.z += w * v.z; s.w += w * v.w;
  }
  *reinterpret_cast<float4*>(&out[(size_t)t * NH + h4]) = s;
}

// ---------------------------------------------------------------------------
extern "C" void kernel_launch(void* const* d_in, const int* in_sizes, int n_in,
                              void* d_out, int out_size, void* d_ws,
                              size_t ws_size, hipStream_t stream) {
  const float* x      = (const float*)d_in[0];
  const float* gate_w = (const float*)d_in[1];
  const float* wg     = (const float*)d_in[2];
  const float* wu     = (const float*)d_in[3];
  const float* wd     = (const float*)d_in[4];

  float* out        = (float*)d_out;
  float* logits_out = (float*)d_out + (size_t)NT * NH;

  char* ws = (char*)d_ws;
  int* cnt            = (int*)(ws + OFF_CNT);
  int* entries        = (int*)(ws + OFF_ENT);
  float* w_tk         = (float*)(ws + OFF_WTK);
  int* tile_hdr       = (int*)(ws + OFF_TIL);
  unsigned short* xb  = (unsigned short*)(ws + OFF_XB);
  unsigned short* act = (unsigned short*)(ws + OFF_ACT);
  float* yp           = (float*)(ws + OFF_YP);

  hipMemsetAsync(ws, 0, 1024, stream);  // zero expert counters

  router_kernel<<<NT, 256, 0, stream>>>(x, gate_w, logits_out, cnt, entries, w_tk, xb);
  build_tiles<<<1, 64, 0, stream>>>(cnt, tile_hdr);
  phase1_mfma<<<dim3(NF / BN, MAXTILES), 512, 0, stream>>>(xb, wg, wu, tile_hdr, entries, cnt, act);
  phase2_mfma<<<dim3(NH / BN, MAXTILES), 512, 0, stream>>>(act, wd, tile_hdr, entries, cnt, yp);
  combine_kernel<<<(NT * NH / 4) / 256, 256, 0, stream>>>(yp, w_tk, out);
}